// Round 6
// baseline (455.332 us; speedup 1.0000x reference)
//
#include <hip/hip_runtime.h>
#include <hip/hip_bf16.h>

// Problem constants
#define NA 8192      // oscillators in bank a (mask rows)
#define NB 8192      // oscillators in bank b (mask cols = GEMM K)
#define NBATCH 64
#define NC 128       // GEMM N: interleaved [cos_b, sin_b] cols, c=2b (cos), 2b+1 (sin)
#define BM 128       // output rows per block
#define WM 32        // output rows per wave (2 A-fragments of 16)
#define SPLITK 16
#define KCHUNK (NB / SPLITK)     // 512
#define NBLK (SPLITK * NA / BM)  // 1024 gemm blocks

// workspace layout
#define XT_BYTES (NC * NB * 2)            // 2 MiB bf16 XtF (fragment-ordered)
#define CTR_OFF  XT_BYTES                 // count (int)
#define PBLK_OFF (CTR_OFF + 512)          // NBLK * 128 f32 block partials (512 KiB)

typedef __bf16 bf16x8 __attribute__((ext_vector_type(8)));
typedef float  f32x4  __attribute__((ext_vector_type(4)));
typedef int    ivec4  __attribute__((ext_vector_type(4)));

// ---------------- prep: phases_b -> XtF in MFMA B-fragment order --------------
// Element (k, c) stored at ((kstep*8 + t)*64 + quad*16 + m)*8 + e
//   kstep=k>>5, quad=(k>>3)&3, e=k&7, t=c>>4, m=c&15  (natural k order)
__global__ __launch_bounds__(256) void prep_b_kernel(
    const float* __restrict__ pb, __hip_bfloat16* __restrict__ Xtf)
{
    int tid = blockIdx.x * 256 + threadIdx.x;   // 0 .. NBATCH*NB-1
    int b = tid >> 13;
    int k = tid & (NB - 1);

    float ph = pb[tid];
    float s, c;
    __sincosf(ph, &s, &c);

    int kstep = k >> 5;
    int quad  = (k >> 3) & 3;
    int e     = k & 7;
    int t     = b >> 3;            // (2b)>>4 == (2b+1)>>4
    int m0    = (2 * b) & 15;
    size_t base = ((size_t)(kstep * 8 + t) * 64 + quad * 16) * 8 + e;
    Xtf[base + (size_t)m0 * 8]       = __float2bfloat16(c);
    Xtf[base + (size_t)(m0 + 1) * 8] = __float2bfloat16(s);
}

// ---------------- fused GEMM + batch-reduce epilogue --------------------------
// P[i][c] = sum_k mask[i][k] * X[k][c]  (never materialized)
// A-frag: 2x nontemporal int4 mask loads/lane; B-frag: coalesced 1 KB from XtF
// C/D: col=lane&15, row=quad*4+reg (measured m89/m91)
// Epilogue: real_b += ca[b,i]*P[i,2b] + sa[b,i]*P[i,2b+1]
//           imag_b += sa[b,i]*P[i,2b] - ca[b,i]*P[i,2b+1]
// reduced per-block into Pblk[bid][2b+comp]; popcount via wave atomic.
__global__ __launch_bounds__(256, 3) void gemm_kernel(
    const int* __restrict__ mask, const __hip_bfloat16* __restrict__ Xtfg,
    const float* __restrict__ pa,
    float* __restrict__ Pblk, int* __restrict__ count)
{
    const int tid  = threadIdx.x;
    const int wave = tid >> 6;
    const int lane = tid & 63;
    const int quad = lane >> 4;
    const int m    = lane & 15;
    const int itile = blockIdx.x;       // 0..63
    const int kc    = blockIdx.y;       // 0..SPLITK-1
    const int k0    = kc * KCHUNK;

    const int rowbase = itile * BM + wave * WM;
    const bf16x8* __restrict__ xf = reinterpret_cast<const bf16x8*>(Xtfg);

    f32x4 acc[2][8];
#pragma unroll
    for (int f = 0; f < 2; ++f)
#pragma unroll
        for (int t = 0; t < 8; ++t)
            acc[f][t] = (f32x4){0.f, 0.f, 0.f, 0.f};

    int cnt = 0;

#pragma unroll 2
    for (int kk = k0; kk < k0 + KCHUNK; kk += 32) {
        const int kq = kk + quad * 8;

        bf16x8 a[2];
#pragma unroll
        for (int f = 0; f < 2; ++f) {
            const ivec4* p = reinterpret_cast<const ivec4*>(
                mask + (size_t)(rowbase + f * 16 + m) * NB + kq);
            ivec4 r0 = __builtin_nontemporal_load(p);
            ivec4 r1 = __builtin_nontemporal_load(p + 1);
            cnt += r0.x + r0.y + r0.z + r0.w + r1.x + r1.y + r1.z + r1.w;
            uint4 u;
            u.x = (r0.x ? 0x3F80u : 0u) | (r0.y ? 0x3F800000u : 0u);
            u.y = (r0.z ? 0x3F80u : 0u) | (r0.w ? 0x3F800000u : 0u);
            u.z = (r1.x ? 0x3F80u : 0u) | (r1.y ? 0x3F800000u : 0u);
            u.w = (r1.z ? 0x3F80u : 0u) | (r1.w ? 0x3F800000u : 0u);
            a[f] = __builtin_bit_cast(bf16x8, u);
        }

        const bf16x8* fx = xf + (size_t)(kk >> 5) * 8 * 64 + lane;
#pragma unroll
        for (int t = 0; t < 8; ++t) {
            const bf16x8 bfrag = fx[t * 64];
            acc[0][t] = __builtin_amdgcn_mfma_f32_16x16x32_bf16(a[0], bfrag, acc[0][t], 0, 0, 0);
            acc[1][t] = __builtin_amdgcn_mfma_f32_16x16x32_bf16(a[1], bfrag, acc[1][t], 0, 0, 0);
        }
    }

    // ---- fused epilogue: project partial P onto (ca,sa) and reduce ----
    __shared__ float lred[4][64][2];
    const int odd = m & 1;

#pragma unroll
    for (int t = 0; t < 8; ++t) {
        const int b = t * 8 + (m >> 1);           // batch index for this column
        float rc = 0.f, ic = 0.f;
#pragma unroll
        for (int f = 0; f < 2; ++f)
#pragma unroll
            for (int r = 0; r < 4; ++r) {
                int row = rowbase + f * 16 + quad * 4 + r;
                float ph = pa[(size_t)b * NA + row];
                float sn, cs;
                __sincosf(ph, &sn, &cs);
                float Ax = odd ? sn : cs;          // real-part weight
                float Bx = odd ? -cs : sn;         // imag-part weight
                rc = fmaf(Ax, acc[f][t][r], rc);
                ic = fmaf(Bx, acc[f][t][r], ic);
            }
        // combine col pair (even+odd), then the 4 quads
        rc += __shfl_xor(rc, 1);  ic += __shfl_xor(ic, 1);
        rc += __shfl_xor(rc, 16); ic += __shfl_xor(ic, 16);
        rc += __shfl_xor(rc, 32); ic += __shfl_xor(ic, 32);
        if (quad == 0 && !odd) {
            lred[wave][b][0] = rc;
            lred[wave][b][1] = ic;
        }
    }
    __syncthreads();

    if (tid < 128) {
        float s = lred[0][tid >> 1][tid & 1] + lred[1][tid >> 1][tid & 1]
                + lred[2][tid >> 1][tid & 1] + lred[3][tid >> 1][tid & 1];
        int bid = blockIdx.y * 64 + blockIdx.x;
        Pblk[(size_t)bid * 128 + tid] = s;
    }

    // mask popcount: wave reduce then one atomic per wave
#pragma unroll
    for (int off = 32; off > 0; off >>= 1) cnt += __shfl_down(cnt, off);
    if (lane == 0) atomicAdd(count, cnt);
}

// ---------------- final: sum block partials, magnitude, normalize -------------
__global__ __launch_bounds__(1024) void final_kernel(
    const float* __restrict__ Pblk, const int* __restrict__ count,
    float* __restrict__ out)
{
    const int t = threadIdx.x;          // 0..1023
    const int grp = t & 7;              // 8 threads per value
    const int idx = t >> 3;             // 0..127 = 2b+comp

    float s = 0.f;
#pragma unroll 8
    for (int blk = grp * (NBLK / 8); blk < (grp + 1) * (NBLK / 8); ++blk)
        s += Pblk[(size_t)blk * 128 + idx];
    s += __shfl_xor(s, 1);
    s += __shfl_xor(s, 2);
    s += __shfl_xor(s, 4);

    __shared__ float red[128];
    if (grp == 0) red[idx] = s;
    __syncthreads();

    if (t < NBATCH) {
        float r = red[2 * t], im = red[2 * t + 1];
        float n = fmaxf((float)(*count), 1.0f);
        out[t] = sqrtf(r * r + im * im) / n;
    }
}

extern "C" void kernel_launch(void* const* d_in, const int* in_sizes, int n_in,
                              void* d_out, int out_size, void* d_ws, size_t ws_size,
                              hipStream_t stream) {
    const float* pa   = (const float*)d_in[0];   // phases_a (64, 8192) f32
    const float* pb   = (const float*)d_in[1];   // phases_b (64, 8192) f32
    const int*   mask = (const int*)d_in[2];     // coupling_mask (8192, 8192) i32
    float* out = (float*)d_out;                  // (64,) f32

    char* ws = (char*)d_ws;
    __hip_bfloat16* Xtf = (__hip_bfloat16*)ws;
    int*   count = (int*)(ws + CTR_OFF);
    float* Pblk  = (float*)(ws + PBLK_OFF);

    // zero the popcount accumulator (ws is poisoned 0xAA before each call)
    hipMemsetAsync(ws + CTR_OFF, 0, 512, stream);

    prep_b_kernel<<<(NBATCH * NB) / 256, 256, 0, stream>>>(pb, Xtf);

    dim3 g(NA / BM, SPLITK);
    gemm_kernel<<<g, 256, 0, stream>>>(mask, Xtf, pa, Pblk, count);

    final_kernel<<<1, 1024, 0, stream>>>(Pblk, count, out);
}

// Round 7
// 418.157 us; speedup vs baseline: 1.0889x; 1.0889x over previous
//
#include <hip/hip_runtime.h>
#include <hip/hip_bf16.h>

// Problem constants
#define NA 8192      // oscillators in bank a (mask rows)
#define NB 8192      // oscillators in bank b (mask cols = GEMM K)
#define NBATCH 64
#define NC 128       // GEMM N: interleaved [cos_b, sin_b] cols, c=2b (cos), 2b+1 (sin)
#define BM 128       // output rows per block
#define WM 32        // output rows per wave (2 A-fragments of 16)
#define SPLITK 8
#define KCHUNK (NB / SPLITK)     // 1024
#define NBLK (SPLITK * NA / BM)  // 512 gemm blocks

// workspace layout
#define XT_BYTES (NC * NB * 2)            // 2 MiB bf16 XtF (fragment-ordered)
#define CTR_OFF  XT_BYTES                 // count (int)
#define PBLK_OFF (CTR_OFF + 512)          // NBLK * 128 f32 block partials (256 KiB)

typedef __bf16 bf16x8 __attribute__((ext_vector_type(8)));
typedef float  f32x4  __attribute__((ext_vector_type(4)));
typedef int    ivec4  __attribute__((ext_vector_type(4)));

// ---------------- prep: phases_b -> XtF in MFMA B-fragment order --------------
// Element (k, c) stored at ((kstep*8 + t)*64 + quad*16 + m)*8 + e
//   kstep=k>>5, quad=(k>>3)&3, e=k&7, t=c>>4, m=c&15  (natural k order)
// Also zeroes the popcount accumulator (replaces a hipMemsetAsync launch;
// visibility to the later gemm launch is guaranteed by stream ordering).
__global__ __launch_bounds__(256) void prep_b_kernel(
    const float* __restrict__ pb, __hip_bfloat16* __restrict__ Xtf,
    int* __restrict__ count)
{
    int tid = blockIdx.x * 256 + threadIdx.x;   // 0 .. NBATCH*NB-1
    if (tid == 0) *count = 0;

    int b = tid >> 13;
    int k = tid & (NB - 1);

    float ph = pb[tid];
    float s, c;
    __sincosf(ph, &s, &c);

    int kstep = k >> 5;
    int quad  = (k >> 3) & 3;
    int e     = k & 7;
    int t     = b >> 3;            // (2b)>>4 == (2b+1)>>4
    int m0    = (2 * b) & 15;
    size_t base = ((size_t)(kstep * 8 + t) * 64 + quad * 16) * 8 + e;
    Xtf[base + (size_t)m0 * 8]       = __float2bfloat16(c);
    Xtf[base + (size_t)(m0 + 1) * 8] = __float2bfloat16(s);
}

// ---------------- fused GEMM + batch-reduce epilogue --------------------------
// P[i][c] = sum_k mask[i][k] * X[k][c]  (never materialized)
// A-frag: 2x nontemporal int4 mask loads/lane; B-frag: coalesced 1 KB from XtF
// C/D: col=lane&15, row=quad*4+reg (measured m89/m91)
// Epilogue: real_b += ca[b,i]*P[i,2b] + sa[b,i]*P[i,2b+1]
//           imag_b += sa[b,i]*P[i,2b] - ca[b,i]*P[i,2b+1]
// reduced per-block into Pblk[bid][2b+comp]; popcount via wave atomic.
// NOTE: __launch_bounds__(256,2) + no k-loop unroll is the measured optimum —
// (256,3)+unroll2 regressed 420->455 us (VGPR cap ~170 forces spills whose
// scratch traffic adds to the HBM mask stream). Do not re-raise.
__global__ __launch_bounds__(256, 2) void gemm_kernel(
    const int* __restrict__ mask, const __hip_bfloat16* __restrict__ Xtfg,
    const float* __restrict__ pa,
    float* __restrict__ Pblk, int* __restrict__ count)
{
    const int tid  = threadIdx.x;
    const int wave = tid >> 6;
    const int lane = tid & 63;
    const int quad = lane >> 4;
    const int m    = lane & 15;
    const int itile = blockIdx.x;       // 0..63
    const int kc    = blockIdx.y;       // 0..SPLITK-1
    const int k0    = kc * KCHUNK;

    const int rowbase = itile * BM + wave * WM;
    const bf16x8* __restrict__ xf = reinterpret_cast<const bf16x8*>(Xtfg);

    f32x4 acc[2][8];
#pragma unroll
    for (int f = 0; f < 2; ++f)
#pragma unroll
        for (int t = 0; t < 8; ++t)
            acc[f][t] = (f32x4){0.f, 0.f, 0.f, 0.f};

    int cnt = 0;

    for (int kk = k0; kk < k0 + KCHUNK; kk += 32) {
        const int kq = kk + quad * 8;

        bf16x8 a[2];
#pragma unroll
        for (int f = 0; f < 2; ++f) {
            const ivec4* p = reinterpret_cast<const ivec4*>(
                mask + (size_t)(rowbase + f * 16 + m) * NB + kq);
            ivec4 r0 = __builtin_nontemporal_load(p);
            ivec4 r1 = __builtin_nontemporal_load(p + 1);
            cnt += r0.x + r0.y + r0.z + r0.w + r1.x + r1.y + r1.z + r1.w;
            uint4 u;
            u.x = (r0.x ? 0x3F80u : 0u) | (r0.y ? 0x3F800000u : 0u);
            u.y = (r0.z ? 0x3F80u : 0u) | (r0.w ? 0x3F800000u : 0u);
            u.z = (r1.x ? 0x3F80u : 0u) | (r1.y ? 0x3F800000u : 0u);
            u.w = (r1.z ? 0x3F80u : 0u) | (r1.w ? 0x3F800000u : 0u);
            a[f] = __builtin_bit_cast(bf16x8, u);
        }

        const bf16x8* fx = xf + (size_t)(kk >> 5) * 8 * 64 + lane;
#pragma unroll
        for (int t = 0; t < 8; ++t) {
            const bf16x8 bfrag = fx[t * 64];
            acc[0][t] = __builtin_amdgcn_mfma_f32_16x16x32_bf16(a[0], bfrag, acc[0][t], 0, 0, 0);
            acc[1][t] = __builtin_amdgcn_mfma_f32_16x16x32_bf16(a[1], bfrag, acc[1][t], 0, 0, 0);
        }
    }

    // ---- fused epilogue: project partial P onto (ca,sa) and reduce ----
    __shared__ float lred[4][64][2];
    const int odd = m & 1;

#pragma unroll
    for (int t = 0; t < 8; ++t) {
        const int b = t * 8 + (m >> 1);           // batch index for this column
        float rc = 0.f, ic = 0.f;
#pragma unroll
        for (int f = 0; f < 2; ++f)
#pragma unroll
            for (int r = 0; r < 4; ++r) {
                int row = rowbase + f * 16 + quad * 4 + r;
                float ph = pa[(size_t)b * NA + row];
                float sn, cs;
                __sincosf(ph, &sn, &cs);
                float Ax = odd ? sn : cs;          // real-part weight
                float Bx = odd ? -cs : sn;         // imag-part weight
                rc = fmaf(Ax, acc[f][t][r], rc);
                ic = fmaf(Bx, acc[f][t][r], ic);
            }
        // combine col pair (even+odd), then the 4 quads
        rc += __shfl_xor(rc, 1);  ic += __shfl_xor(ic, 1);
        rc += __shfl_xor(rc, 16); ic += __shfl_xor(ic, 16);
        rc += __shfl_xor(rc, 32); ic += __shfl_xor(ic, 32);
        if (quad == 0 && !odd) {
            lred[wave][b][0] = rc;
            lred[wave][b][1] = ic;
        }
    }
    __syncthreads();

    if (tid < 128) {
        float s = lred[0][tid >> 1][tid & 1] + lred[1][tid >> 1][tid & 1]
                + lred[2][tid >> 1][tid & 1] + lred[3][tid >> 1][tid & 1];
        int bid = blockIdx.y * 64 + blockIdx.x;
        Pblk[(size_t)bid * 128 + tid] = s;
    }

    // mask popcount: wave reduce then one atomic per wave
#pragma unroll
    for (int off = 32; off > 0; off >>= 1) cnt += __shfl_down(cnt, off);
    if (lane == 0) atomicAdd(count, cnt);
}

// ---------------- final: sum block partials, magnitude, normalize -------------
__global__ __launch_bounds__(512) void final_kernel(
    const float* __restrict__ Pblk, const int* __restrict__ count,
    float* __restrict__ out)
{
    const int t = threadIdx.x;          // 0..511
    const int grp = t & 3;              // 4 threads per value
    const int idx = t >> 2;             // 0..127 = 2b+comp

    float s = 0.f;
#pragma unroll 8
    for (int blk = grp * (NBLK / 4); blk < (grp + 1) * (NBLK / 4); ++blk)
        s += Pblk[(size_t)blk * 128 + idx];
    s += __shfl_xor(s, 1);
    s += __shfl_xor(s, 2);

    __shared__ float red[128];
    if (grp == 0) red[idx] = s;
    __syncthreads();

    if (t < NBATCH) {
        float r = red[2 * t], im = red[2 * t + 1];
        float n = fmaxf((float)(*count), 1.0f);
        out[t] = sqrtf(r * r + im * im) / n;
    }
}

extern "C" void kernel_launch(void* const* d_in, const int* in_sizes, int n_in,
                              void* d_out, int out_size, void* d_ws, size_t ws_size,
                              hipStream_t stream) {
    const float* pa   = (const float*)d_in[0];   // phases_a (64, 8192) f32
    const float* pb   = (const float*)d_in[1];   // phases_b (64, 8192) f32
    const int*   mask = (const int*)d_in[2];     // coupling_mask (8192, 8192) i32
    float* out = (float*)d_out;                  // (64,) f32

    char* ws = (char*)d_ws;
    __hip_bfloat16* Xtf = (__hip_bfloat16*)ws;
    int*   count = (int*)(ws + CTR_OFF);
    float* Pblk  = (float*)(ws + PBLK_OFF);

    prep_b_kernel<<<(NBATCH * NB) / 256, 256, 0, stream>>>(pb, Xtf, count);

    dim3 g(NA / BM, SPLITK);
    gemm_kernel<<<g, 256, 0, stream>>>(mask, Xtf, pa, Pblk, count);

    final_kernel<<<1, 512, 0, stream>>>(Pblk, count, out);
}